// Round 1
// baseline (707.121 us; speedup 1.0000x reference)
//
#include <hip/hip_runtime.h>

#define DIM    192
#define HEADS  6
#define NTOK   49
#define NWIN   64

typedef __attribute__((ext_vector_type(8))) short short8;
typedef __attribute__((ext_vector_type(4))) float f32x4;

// LDS strides (elements). All bf16 row strides give 16B-aligned ds_read_b128
// (stride*2 % 16 == 0) and bank stride 4 (2-way conflict = free per m136).
#define XS 200   // sx / sq / sk row stride (bf16), 192 cols + pad
#define VS 72    // sv (V^T) row stride (bf16), 64 tokens + pad
#define SS 65    // S row stride (fp32)
#define PS 72    // P row stride (bf16)

#define BIAS_ELEMS (HEADS * NTOK * NTOK)             // 14406 floats
#define WQKV_SOFF   28864                            // ushort offset in ws (57728 B)
#define WQKV_ELEMS  (3 * DIM * DIM)                  // 110592
#define WPROJ_SOFF  (WQKV_SOFF + WQKV_ELEMS)         // 139456
#define WPROJ_ELEMS (DIM * DIM)                      // 36864

__device__ __forceinline__ unsigned short f2bf(float f) {
    unsigned int u = __float_as_uint(f);
    u += 0x7FFFu + ((u >> 16) & 1u);   // round-to-nearest-even
    return (unsigned short)(u >> 16);
}

// ---------------- K1: bias gather + bf16 weight conversion ----------------
__global__ void wa_prep_kernel(const int* __restrict__ rpi,
                               const float* __restrict__ rpb,
                               const float* __restrict__ qkv_w,
                               const float* __restrict__ proj_w,
                               float* __restrict__ bias,
                               unsigned short* __restrict__ wqkv,
                               unsigned short* __restrict__ wproj) {
    __shared__ int is64_s;
    if (threadIdx.x == 0) {
        int zeros = 0;
        for (int p = 0; p < 64; ++p) zeros += (rpi[2 * p + 1] == 0) ? 1 : 0;
        is64_s = (zeros >= 48) ? 1 : 0;
    }
    __syncthreads();
    const int is64 = is64_s;
    const int total = BIAS_ELEMS + WQKV_ELEMS + WPROJ_ELEMS;
    for (int idx = blockIdx.x * blockDim.x + threadIdx.x; idx < total;
         idx += gridDim.x * blockDim.x) {
        if (idx < BIAS_ELEMS) {
            int h  = idx / (NTOK * NTOK);
            int nm = idx - h * (NTOK * NTOK);
            int r  = is64 ? rpi[2 * nm] : rpi[nm];
            bias[idx] = rpb[r * HEADS + h];
        } else if (idx < BIAS_ELEMS + WQKV_ELEMS) {
            int i = idx - BIAS_ELEMS;
            wqkv[i] = f2bf(qkv_w[i]);
        } else {
            int i = idx - BIAS_ELEMS - WQKV_ELEMS;
            wproj[i] = f2bf(proj_w[i]);
        }
    }
}

// ---------------- K2: fused QKV + attention + output projection ----------------
// One block per window. After head h's 2a phase, sq columns [32h,32h+32) are
// dead (Q for head h fully consumed), so 2c writes head h's attention output
// (bf16, sinv-scaled) into exactly those columns. After the head loop, sq
// holds the full 64x192 attention output and the proj GEMM runs in-block
// against L2-resident wproj — this replaces the former K3 kernel (one full
// 154MB+154MB out round-trip eliminated).
__global__ __launch_bounds__(512, 1)
void wa_attn_kernel(const float* __restrict__ x,
                    const float* __restrict__ maskp,
                    const unsigned short* __restrict__ wqkv,
                    const float* __restrict__ qkv_b,
                    const float* __restrict__ biasp,
                    const unsigned short* __restrict__ wproj,
                    const float* __restrict__ proj_b,
                    float* __restrict__ out) {
    // union region: phase<=1 uses sx (25600 B); phase 2 uses S (16640 B) + P (9216 B)
    __shared__ __attribute__((aligned(16))) float uSP[64 * SS + 64 * (PS / 2)]; // 25856 B
    __shared__ __attribute__((aligned(16))) unsigned short sq[64 * XS];   // 25600 B
    __shared__ __attribute__((aligned(16))) unsigned short sk[64 * XS];   // 25600 B
    __shared__ __attribute__((aligned(16))) unsigned short sv[DIM * VS];  // 27648 B (V^T)
    __shared__ float sinv[64];

    unsigned short* sx = (unsigned short*)uSP;
    float* S = uSP;
    unsigned short* P = (unsigned short*)(uSP + 64 * SS);

    const int tid  = threadIdx.x;
    const int wave = tid >> 6;
    const int lane = tid & 63;
    const int quad = lane >> 4;
    const int l16  = lane & 15;
    const int bw   = blockIdx.x;
    const int win  = bw & (NWIN - 1);

    // ---- phase 0: stage x window fp32 -> bf16 LDS, zero pad rows 49..63 ----
    {
        const float4* xw = (const float4*)(x + (size_t)bw * (NTOK * DIM));
        for (int idx = tid; idx < NTOK * DIM / 4; idx += 512) {
            int row = idx / 48, c4 = idx - row * 48;
            float4 v = xw[idx];
            unsigned int lo = (unsigned int)f2bf(v.x) | ((unsigned int)f2bf(v.y) << 16);
            unsigned int hi = (unsigned int)f2bf(v.z) | ((unsigned int)f2bf(v.w) << 16);
            *(uint2*)&sx[row * XS + c4 * 4] = make_uint2(lo, hi);
        }
        for (int idx = tid; idx < 15 * 24; idx += 512) {
            int row = 49 + idx / 24, c8 = idx - (idx / 24) * 24;
            *(uint4*)&sx[row * XS + c8 * 8] = make_uint4(0, 0, 0, 0);
        }
    }
    __syncthreads();

    // ---- phase 1: QKV = X * Wqkv^T + b  (MFMA; B-frags from L2-resident bf16 weights) ----
    // NOTE: r-loops MUST be compile-time unrolled with static acc indices;
    // a runtime trip count (round-2 bug) demoted acc[][] to scratch -> 8 GB
    // of hidden HBM traffic (WRITE_SIZE 4.1 GB, VGPR_Count 88).
    {
        f32x4 acc[5][4];
        #pragma unroll
        for (int r = 0; r < 5; ++r)
            #pragma unroll
            for (int mt = 0; mt < 4; ++mt) acc[r][mt] = (f32x4){0.f, 0.f, 0.f, 0.f};
        for (int k0 = 0; k0 < DIM; k0 += 32) {
            short8 af[4];
            #pragma unroll
            for (int mt = 0; mt < 4; ++mt)
                af[mt] = *(const short8*)&sx[(mt * 16 + l16) * XS + k0 + quad * 8];
            #pragma unroll
            for (int r = 0; r < 5; ++r) {
                if (wave >= 4 && r == 4) continue;   // 36 N-tiles over 8 waves
                int n0 = (wave + 8 * r) * 16;
                short8 bf = *(const short8*)(wqkv + (n0 + l16) * DIM + k0 + quad * 8);
                #pragma unroll
                for (int mt = 0; mt < 4; ++mt)
                    acc[r][mt] = __builtin_amdgcn_mfma_f32_16x16x32_bf16(af[mt], bf, acc[r][mt], 0, 0, 0);
            }
        }
        #pragma unroll
        for (int r = 0; r < 5; ++r) {
            if (wave >= 4 && r == 4) continue;
            int n0  = (wave + 8 * r) * 16;
            int col = n0 + l16;
            float cb = qkv_b[col];
            #pragma unroll
            for (int mt = 0; mt < 4; ++mt) {
                #pragma unroll
                for (int rr = 0; rr < 4; ++rr) {
                    int m = mt * 16 + quad * 4 + rr;    // C/D: row=quad*4+reg, col=l16
                    unsigned short bv = f2bf(acc[r][mt][rr] + cb);
                    if (col < 192)      sq[m * XS + col] = bv;
                    else if (col < 384) sk[m * XS + (col - 192)] = bv;
                    else                sv[(col - 384) * VS + m] = bv;   // V transposed
                }
            }
        }
    }
    __syncthreads();

    const float scale = 0.17677669529663687f;
    const float* maskw = maskp + win * (NTOK * NTOK);

    for (int h = 0; h < HEADS; ++h) {
        // ---- 2a: S = scale * Q_h K_h^T + bias + mask (16 tiles, 2 per wave) ----
        {
            f32x4 zz = {0.f, 0.f, 0.f, 0.f};
            const float* bh = biasp + h * (NTOK * NTOK);
            #pragma unroll
            for (int tt = 0; tt < 2; ++tt) {
                int t = wave * 2 + tt;
                int mt = t >> 2, nt = t & 3;
                short8 af = *(const short8*)&sq[(mt * 16 + l16) * XS + h * 32 + quad * 8];
                short8 bf = *(const short8*)&sk[(nt * 16 + l16) * XS + h * 32 + quad * 8];
                f32x4 d = __builtin_amdgcn_mfma_f32_16x16x32_bf16(af, bf, zz, 0, 0, 0);
                #pragma unroll
                for (int rr = 0; rr < 4; ++rr) {
                    int i = mt * 16 + quad * 4 + rr;
                    int j = nt * 16 + l16;
                    float sval = -30000.f;   // pad -> exp underflows to 0
                    if (i < NTOK && j < NTOK)
                        sval = d[rr] * scale + bh[i * NTOK + j] + maskw[i * NTOK + j];
                    S[i * SS + j] = sval;
                }
            }
        }
        __syncthreads();
        // ---- 2b: softmax rows (8 threads/row) -> bf16 P (unnormalized), sinv ----
        if (tid < 392) {
            int i = tid >> 3, s = tid & 7;
            float m = -1e30f;
            for (int jj = 0; jj < 7; ++jj) {
                int j = s + 8 * jj;
                if (j < NTOK) m = fmaxf(m, S[i * SS + j]);
            }
            for (int o = 1; o < 8; o <<= 1) m = fmaxf(m, __shfl_xor(m, o));
            float sum = 0.f;
            #pragma unroll
            for (int jj = 0; jj < 8; ++jj) {
                int j = s + 8 * jj;                    // covers 0..63 (pads -> 0)
                float e = 0.f;
                if (j < NTOK) { e = __expf(S[i * SS + j] - m); sum += e; }
                P[i * PS + j] = f2bf(e);
            }
            for (int o = 1; o < 8; o <<= 1) sum += __shfl_xor(sum, o);
            if (s == 0) sinv[i] = 1.f / sum;
        }
        __syncthreads();
        // ---- 2c: O_h = (P V) * sinv -> bf16 into sq cols [32h, 32h+32)  ----
        // sq cols of head h are dead after the 2b barrier (all waves passed 2a).
        // Pad rows 49..63 get explicit zeros so the proj A-operand is clean.
        {
            int mt = wave >> 1, nt = wave & 1;
            f32x4 acc = {0.f, 0.f, 0.f, 0.f};
            #pragma unroll
            for (int k0 = 0; k0 < 64; k0 += 32) {
                short8 af = *(const short8*)&P[(mt * 16 + l16) * PS + k0 + quad * 8];
                short8 bf = *(const short8*)&sv[(h * 32 + nt * 16 + l16) * VS + k0 + quad * 8];
                acc = __builtin_amdgcn_mfma_f32_16x16x32_bf16(af, bf, acc, 0, 0, 0);
            }
            #pragma unroll
            for (int rr = 0; rr < 4; ++rr) {
                int i = mt * 16 + quad * 4 + rr;
                unsigned short ov = 0;
                if (i < NTOK) ov = f2bf(acc[rr] * sinv[i]);
                sq[i * XS + h * 32 + nt * 16 + l16] = ov;
            }
        }
        // no end-of-loop barrier needed: next 2a writes S only (disjoint from P/sv/sinv)
        // and reads sq cols of head h+1 (disjoint from this 2c's writes to cols of h);
        // the post-2a barrier orders this 2c's P/sinv reads before next 2b's writes.
    }
    __syncthreads();

    // ---- phase 3: fused output projection  out = O @ proj_w^T + proj_b ----
    // A = sq (64x192 bf16, pad rows zeroed), B = wproj (L2-resident).
    // 48 output tiles: waves split 2-way on M (mh) x 4-way on N (wv), 3 N-tiles each.
    {
        const int mh = wave >> 2;    // 0..1 -> mt pair {2mh, 2mh+1}
        const int wv = wave & 3;     // 0..3 -> n-tiles wv, wv+4, wv+8
        f32x4 pacc[3][2];
        #pragma unroll
        for (int r = 0; r < 3; ++r)
            #pragma unroll
            for (int mi = 0; mi < 2; ++mi) pacc[r][mi] = (f32x4){0.f, 0.f, 0.f, 0.f};
        for (int k0 = 0; k0 < DIM; k0 += 32) {
            short8 af[2];
            #pragma unroll
            for (int mi = 0; mi < 2; ++mi)
                af[mi] = *(const short8*)&sq[((mh * 2 + mi) * 16 + l16) * XS + k0 + quad * 8];
            #pragma unroll
            for (int r = 0; r < 3; ++r) {
                int n0 = (wv + 4 * r) * 16;
                short8 bf = *(const short8*)(wproj + (n0 + l16) * DIM + k0 + quad * 8);
                #pragma unroll
                for (int mi = 0; mi < 2; ++mi)
                    pacc[r][mi] = __builtin_amdgcn_mfma_f32_16x16x32_bf16(af[mi], bf, pacc[r][mi], 0, 0, 0);
            }
        }
        #pragma unroll
        for (int r = 0; r < 3; ++r) {
            int n0 = (wv + 4 * r) * 16;
            float cb = proj_b[n0 + l16];
            #pragma unroll
            for (int mi = 0; mi < 2; ++mi) {
                #pragma unroll
                for (int rr = 0; rr < 4; ++rr) {
                    int m = (mh * 2 + mi) * 16 + quad * 4 + rr;
                    if (m < NTOK)
                        out[((size_t)bw * NTOK + m) * DIM + n0 + l16] = pacc[r][mi][rr] + cb;
                }
            }
        }
    }
}

extern "C" void kernel_launch(void* const* d_in, const int* in_sizes, int n_in,
                              void* d_out, int out_size, void* d_ws, size_t ws_size,
                              hipStream_t stream) {
    const float* x      = (const float*)d_in[0];
    const int*   rpi    = (const int*)d_in[1];
    const float* maskp  = (const float*)d_in[2];
    const float* qkv_w  = (const float*)d_in[3];
    const float* qkv_b  = (const float*)d_in[4];
    const float* proj_w = (const float*)d_in[5];
    const float* proj_b = (const float*)d_in[6];
    const float* rpb    = (const float*)d_in[7];
    float* out = (float*)d_out;

    float* bias = (float*)d_ws;                                   // 57624 B
    unsigned short* wqkv  = (unsigned short*)d_ws + WQKV_SOFF;    // 221184 B
    unsigned short* wproj = (unsigned short*)d_ws + WPROJ_SOFF;   // 73728 B

    wa_prep_kernel<<<320, 256, 0, stream>>>(rpi, rpb, qkv_w, proj_w, bias, wqkv, wproj);
    wa_attn_kernel<<<4096, 512, 0, stream>>>(x, maskp, wqkv, qkv_b, bias, wproj, proj_b, out);
}

// Round 2
// 619.440 us; speedup vs baseline: 1.1416x; 1.1416x over previous
//
#include <hip/hip_runtime.h>

#define DIM    192
#define HEADS  6
#define NTOK   49
#define NWIN   64

typedef __attribute__((ext_vector_type(8))) short short8;
typedef __attribute__((ext_vector_type(4))) float f32x4;

// LDS strides (elements). All bf16 row strides give 16B-aligned ds_read_b128
// (stride*2 % 16 == 0) and bank stride 4 (2-way conflict = free per m136).
#define XS 200   // sx / sq / kstage row stride (bf16), 192 cols + pad
#define VS 72    // sv (V^T) row stride (bf16), 64 tokens + pad
#define SS 65    // S row stride (fp32)
#define PS 72    // P row stride (bf16)

#define BIAS_ELEMS (HEADS * NTOK * NTOK)             // 14406 floats
#define WQKV_SOFF   28864                            // ushort offset in ws (57728 B)
#define WQKV_ELEMS  (3 * DIM * DIM)                  // 110592
#define WPROJ_SOFF  (WQKV_SOFF + WQKV_ELEMS)         // 139456
#define WPROJ_ELEMS (DIM * DIM)                      // 36864

__device__ __forceinline__ unsigned short f2bf(float f) {
    unsigned int u = __float_as_uint(f);
    u += 0x7FFFu + ((u >> 16) & 1u);   // round-to-nearest-even
    return (unsigned short)(u >> 16);
}

// ---------------- K1: bias gather + bf16 weight conversion ----------------
__global__ void wa_prep_kernel(const int* __restrict__ rpi,
                               const float* __restrict__ rpb,
                               const float* __restrict__ qkv_w,
                               const float* __restrict__ proj_w,
                               float* __restrict__ bias,
                               unsigned short* __restrict__ wqkv,
                               unsigned short* __restrict__ wproj) {
    __shared__ int is64_s;
    if (threadIdx.x == 0) {
        int zeros = 0;
        for (int p = 0; p < 64; ++p) zeros += (rpi[2 * p + 1] == 0) ? 1 : 0;
        is64_s = (zeros >= 48) ? 1 : 0;
    }
    __syncthreads();
    const int is64 = is64_s;
    const int total = BIAS_ELEMS + WQKV_ELEMS + WPROJ_ELEMS;
    for (int idx = blockIdx.x * blockDim.x + threadIdx.x; idx < total;
         idx += gridDim.x * blockDim.x) {
        if (idx < BIAS_ELEMS) {
            int h  = idx / (NTOK * NTOK);
            int nm = idx - h * (NTOK * NTOK);
            int r  = is64 ? rpi[2 * nm] : rpi[nm];
            bias[idx] = rpb[r * HEADS + h];
        } else if (idx < BIAS_ELEMS + WQKV_ELEMS) {
            int i = idx - BIAS_ELEMS;
            wqkv[i] = f2bf(qkv_w[i]);
        } else {
            int i = idx - BIAS_ELEMS - WQKV_ELEMS;
            wproj[i] = f2bf(proj_w[i]);
        }
    }
}

// ---------------- K2: fused QKV + attention + output projection ----------------
// One block per window, 2 blocks/CU (LDS 79360 B <= 80 KiB).
// K lives in REGISTERS during the head loop (48 VGPR/lane: 2 tiles x 6 heads x
// short8), freeing the old sk region. The union region uSP serves three lives:
//   phase 0/1: sx (staged x, bf16)  ->  phase 1 epilogue: kstage (K, bf16)
//   -> head loop: S (fp32 scores) + P (bf16 probs).
// After head h, sq cols [32h,32h+32) hold the attention output (Q dead), and
// phase 3 runs the output projection in-block against L2-resident wproj.
__global__ __launch_bounds__(512, 4)
void wa_attn_kernel(const float* __restrict__ x,
                    const float* __restrict__ maskp,
                    const unsigned short* __restrict__ wqkv,
                    const float* __restrict__ qkv_b,
                    const float* __restrict__ biasp,
                    const unsigned short* __restrict__ wproj,
                    const float* __restrict__ proj_b,
                    float* __restrict__ out) {
    __shared__ __attribute__((aligned(16))) float uSP[64 * SS + 64 * (PS / 2)]; // 25856 B
    __shared__ __attribute__((aligned(16))) unsigned short sq[64 * XS];   // 25600 B
    __shared__ __attribute__((aligned(16))) unsigned short sv[DIM * VS];  // 27648 B (V^T)
    __shared__ float sinv[64];

    unsigned short* sx     = (unsigned short*)uSP;
    unsigned short* kstage = (unsigned short*)uSP;
    float* S = uSP;
    unsigned short* P = (unsigned short*)(uSP + 64 * SS);

    const int tid  = threadIdx.x;
    const int wave = tid >> 6;
    const int lane = tid & 63;
    const int quad = lane >> 4;
    const int l16  = lane & 15;
    const int bw   = blockIdx.x;
    const int win  = bw & (NWIN - 1);

    // ---- phase 0: stage x window fp32 -> bf16 LDS, zero pad rows 49..63 ----
    {
        const float4* xw = (const float4*)(x + (size_t)bw * (NTOK * DIM));
        for (int idx = tid; idx < NTOK * DIM / 4; idx += 512) {
            int row = idx / 48, c4 = idx - row * 48;
            float4 v = xw[idx];
            unsigned int lo = (unsigned int)f2bf(v.x) | ((unsigned int)f2bf(v.y) << 16);
            unsigned int hi = (unsigned int)f2bf(v.z) | ((unsigned int)f2bf(v.w) << 16);
            *(uint2*)&sx[row * XS + c4 * 4] = make_uint2(lo, hi);
        }
        for (int idx = tid; idx < 15 * 24; idx += 512) {
            int row = 49 + idx / 24, c8 = idx - (idx / 24) * 24;
            *(uint4*)&sx[row * XS + c8 * 8] = make_uint4(0, 0, 0, 0);
        }
    }
    __syncthreads();

    // ---- phase 1: QKV = X * Wqkv^T + b  (MFMA; B-frags from L2-resident bf16 weights) ----
    // NOTE: r-loops MUST be compile-time unrolled with static acc indices;
    // a runtime trip count (round-2 bug) demoted acc[][] to scratch -> 8 GB
    // of hidden HBM traffic (WRITE_SIZE 4.1 GB, VGPR_Count 88).
    {
        f32x4 acc[5][4];
        #pragma unroll
        for (int r = 0; r < 5; ++r)
            #pragma unroll
            for (int mt = 0; mt < 4; ++mt) acc[r][mt] = (f32x4){0.f, 0.f, 0.f, 0.f};
        for (int k0 = 0; k0 < DIM; k0 += 32) {
            short8 af[4];
            #pragma unroll
            for (int mt = 0; mt < 4; ++mt)
                af[mt] = *(const short8*)&sx[(mt * 16 + l16) * XS + k0 + quad * 8];
            #pragma unroll
            for (int r = 0; r < 5; ++r) {
                if (wave >= 4 && r == 4) continue;   // 36 N-tiles over 8 waves
                int n0 = (wave + 8 * r) * 16;
                short8 bf = *(const short8*)(wqkv + (n0 + l16) * DIM + k0 + quad * 8);
                #pragma unroll
                for (int mt = 0; mt < 4; ++mt)
                    acc[r][mt] = __builtin_amdgcn_mfma_f32_16x16x32_bf16(af[mt], bf, acc[r][mt], 0, 0, 0);
            }
        }
        __syncthreads();   // all sx reads done before K overwrites the union region
        #pragma unroll
        for (int r = 0; r < 5; ++r) {
            if (wave >= 4 && r == 4) continue;
            int n0  = (wave + 8 * r) * 16;
            int col = n0 + l16;
            float cb = qkv_b[col];
            #pragma unroll
            for (int mt = 0; mt < 4; ++mt) {
                #pragma unroll
                for (int rr = 0; rr < 4; ++rr) {
                    int m = mt * 16 + quad * 4 + rr;    // C/D: row=quad*4+reg, col=l16
                    unsigned short bv = f2bf(acc[r][mt][rr] + cb);
                    if (col < 192)      sq[m * XS + col] = bv;
                    else if (col < 384) kstage[m * XS + (col - 192)] = bv;
                    else                sv[(col - 384) * VS + m] = bv;   // V transposed
                }
            }
        }
    }
    __syncthreads();

    // ---- K -> registers: each wave snapshots its 12 B-fragments ----
    short8 kf[2][HEADS];
    #pragma unroll
    for (int tt = 0; tt < 2; ++tt) {
        int t = wave * 2 + tt, nt = t & 3;
        #pragma unroll
        for (int h = 0; h < HEADS; ++h)
            kf[tt][h] = *(const short8*)&kstage[(nt * 16 + l16) * XS + h * 32 + quad * 8];
    }
    __syncthreads();   // K reads done before 2a writes S into the same region

    const float scale = 0.17677669529663687f;
    const float* maskw = maskp + win * (NTOK * NTOK);

    #pragma unroll
    for (int h = 0; h < HEADS; ++h) {
        // ---- 2a: S = scale * Q_h K_h^T + bias + mask (16 tiles, 2 per wave) ----
        {
            f32x4 zz = {0.f, 0.f, 0.f, 0.f};
            const float* bh = biasp + h * (NTOK * NTOK);
            #pragma unroll
            for (int tt = 0; tt < 2; ++tt) {
                int t = wave * 2 + tt;
                int mt = t >> 2, nt = t & 3;
                short8 af = *(const short8*)&sq[(mt * 16 + l16) * XS + h * 32 + quad * 8];
                f32x4 d = __builtin_amdgcn_mfma_f32_16x16x32_bf16(af, kf[tt][h], zz, 0, 0, 0);
                #pragma unroll
                for (int rr = 0; rr < 4; ++rr) {
                    int i = mt * 16 + quad * 4 + rr;
                    int j = nt * 16 + l16;
                    if (i < NTOK && j < NTOK)   // pads never read by 2b
                        S[i * SS + j] = d[rr] * scale + bh[i * NTOK + j] + maskw[i * NTOK + j];
                }
            }
        }
        __syncthreads();
        // ---- 2b: softmax rows (8 threads/row) -> bf16 P (unnormalized), sinv ----
        if (tid < 392) {
            int i = tid >> 3, s = tid & 7;
            float m = -1e30f;
            for (int jj = 0; jj < 7; ++jj) {
                int j = s + 8 * jj;
                if (j < NTOK) m = fmaxf(m, S[i * SS + j]);
            }
            for (int o = 1; o < 8; o <<= 1) m = fmaxf(m, __shfl_xor(m, o));
            float sum = 0.f;
            #pragma unroll
            for (int jj = 0; jj < 8; ++jj) {
                int j = s + 8 * jj;                    // covers 0..63 (pads -> 0)
                float e = 0.f;
                if (j < NTOK) { e = __expf(S[i * SS + j] - m); sum += e; }
                P[i * PS + j] = f2bf(e);
            }
            for (int o = 1; o < 8; o <<= 1) sum += __shfl_xor(sum, o);
            if (s == 0) sinv[i] = 1.f / sum;
        }
        __syncthreads();
        // ---- 2c: O_h = (P V) * sinv -> bf16 into sq cols [32h, 32h+32)  ----
        // sq cols of head h are dead after the 2b barrier (all waves passed 2a).
        // Pad rows 49..63 get explicit zeros so the proj A-operand is clean.
        {
            int mt = wave >> 1, nt = wave & 1;
            f32x4 acc = {0.f, 0.f, 0.f, 0.f};
            #pragma unroll
            for (int k0 = 0; k0 < 64; k0 += 32) {
                short8 af = *(const short8*)&P[(mt * 16 + l16) * PS + k0 + quad * 8];
                short8 bf = *(const short8*)&sv[(h * 32 + nt * 16 + l16) * VS + k0 + quad * 8];
                acc = __builtin_amdgcn_mfma_f32_16x16x32_bf16(af, bf, acc, 0, 0, 0);
            }
            #pragma unroll
            for (int rr = 0; rr < 4; ++rr) {
                int i = mt * 16 + quad * 4 + rr;
                unsigned short ov = 0;
                if (i < NTOK) ov = f2bf(acc[rr] * sinv[i]);
                sq[i * XS + h * 32 + nt * 16 + l16] = ov;
            }
        }
        // no end-of-loop barrier needed: next 2a writes S only (disjoint from P/sv/sinv)
        // and reads sq cols of head h+1 (disjoint from this 2c's writes to cols of h);
        // the post-2a barrier orders this 2c's P/sinv reads before next 2b's writes.
    }
    __syncthreads();

    // ---- phase 3: fused output projection  out = O @ proj_w^T + proj_b ----
    // A = sq (64x192 bf16, pad rows zeroed), B = wproj (L2-resident).
    // 48 output tiles: waves split 2-way on M (mh) x 4-way on N (wv), 3 N-tiles each.
    {
        const int mh = wave >> 2;    // 0..1 -> mt pair {2mh, 2mh+1}
        const int wv = wave & 3;     // 0..3 -> n-tiles wv, wv+4, wv+8
        f32x4 pacc[3][2];
        #pragma unroll
        for (int r = 0; r < 3; ++r)
            #pragma unroll
            for (int mi = 0; mi < 2; ++mi) pacc[r][mi] = (f32x4){0.f, 0.f, 0.f, 0.f};
        for (int k0 = 0; k0 < DIM; k0 += 32) {
            short8 af[2];
            #pragma unroll
            for (int mi = 0; mi < 2; ++mi)
                af[mi] = *(const short8*)&sq[((mh * 2 + mi) * 16 + l16) * XS + k0 + quad * 8];
            #pragma unroll
            for (int r = 0; r < 3; ++r) {
                int n0 = (wv + 4 * r) * 16;
                short8 bf = *(const short8*)(wproj + (n0 + l16) * DIM + k0 + quad * 8);
                #pragma unroll
                for (int mi = 0; mi < 2; ++mi)
                    pacc[r][mi] = __builtin_amdgcn_mfma_f32_16x16x32_bf16(af[mi], bf, pacc[r][mi], 0, 0, 0);
            }
        }
        #pragma unroll
        for (int r = 0; r < 3; ++r) {
            int n0 = (wv + 4 * r) * 16;
            float cb = proj_b[n0 + l16];
            #pragma unroll
            for (int mi = 0; mi < 2; ++mi) {
                #pragma unroll
                for (int rr = 0; rr < 4; ++rr) {
                    int m = (mh * 2 + mi) * 16 + quad * 4 + rr;
                    if (m < NTOK)
                        out[((size_t)bw * NTOK + m) * DIM + n0 + l16] = pacc[r][mi][rr] + cb;
                }
            }
        }
    }
}

extern "C" void kernel_launch(void* const* d_in, const int* in_sizes, int n_in,
                              void* d_out, int out_size, void* d_ws, size_t ws_size,
                              hipStream_t stream) {
    const float* x      = (const float*)d_in[0];
    const int*   rpi    = (const int*)d_in[1];
    const float* maskp  = (const float*)d_in[2];
    const float* qkv_w  = (const float*)d_in[3];
    const float* qkv_b  = (const float*)d_in[4];
    const float* proj_w = (const float*)d_in[5];
    const float* proj_b = (const float*)d_in[6];
    const float* rpb    = (const float*)d_in[7];
    float* out = (float*)d_out;

    float* bias = (float*)d_ws;                                   // 57624 B
    unsigned short* wqkv  = (unsigned short*)d_ws + WQKV_SOFF;    // 221184 B
    unsigned short* wproj = (unsigned short*)d_ws + WPROJ_SOFF;   // 73728 B

    wa_prep_kernel<<<320, 256, 0, stream>>>(rpi, rpb, qkv_w, proj_w, bias, wqkv, wproj);
    wa_attn_kernel<<<4096, 512, 0, stream>>>(x, maskp, wqkv, qkv_b, bias, wproj, proj_b, out);
}